// Round 7
// baseline (471.539 us; speedup 1.0000x reference)
//
#include <hip/hip_runtime.h>

#define BB 256
#define TT 1024
#define II 3
#define HH 128
#define OO 3
#define NT 576   // 8 compute waves (512 thr) + 1 store/projection wave (64 thr)

#if __has_builtin(__builtin_amdgcn_exp2f)
#define EXP2F __builtin_amdgcn_exp2f
#else
#define EXP2F exp2f
#endif
#if __has_builtin(__builtin_amdgcn_rcpf)
#define RCPF __builtin_amdgcn_rcpf
#else
#define RCPF(x) (1.0f / (x))
#endif

// tanh(x) = 1 - 2/(e^{2x}+1)
__device__ __forceinline__ float fast_tanh(float x) {
    float e = EXP2F(x * 2.885390081777927f);
    return 1.0f - 2.0f * RCPF(e + 1.0f);
}

// Workgroup barrier that fences LDS only — does NOT drain vmcnt, so global
// stores stay in flight across it. All cross-wave dataflow goes through LDS.
__device__ __forceinline__ void bar_lds() {
    asm volatile("s_waitcnt lgkmcnt(0)\n\ts_barrier" ::: "memory");
}

// p += p(lane ^ pattern) via DPP (pure VALU; keeps the reduce off the LDS pipe)
template <int CTRL>
__device__ __forceinline__ float dpp_add(float p) {
    return p + __uint_as_float(__builtin_amdgcn_update_dpp(
        0, (int)__float_as_uint(p), CTRL, 0xF, 0xF, true));
}
#define DPP_XOR1 0xB1   // quad_perm [1,0,3,2]
#define DPP_XOR2 0x4E   // quad_perm [2,3,0,1]
#define DPP_HMIR 0x141  // row_half_mirror: lane^7 within 8-lane halves
#define DPP_MIRR 0x140  // row_mirror: lane^15 within 16-lane rows

// sum over 4-lane quad via DPP quad_perm (store wave)
__device__ __forceinline__ float quad_reduce(float p) {
    p = dpp_add<DPP_XOR1>(p);
    p = dpp_add<DPP_XOR2>(p);
    return p;
}

// Physical storage permutation for the 128-float hidden state, at float4-chunk
// granularity: logical chunk c (0..31) lives at physical chunk psi(c).
__device__ __forceinline__ int psi(int c) { return (c >> 1) | ((c & 1) << 4); }

// One block per batch element; one s_barrier per timestep (latency-bound).
//
// ROUND 7 CHANGE (isolated): __launch_bounds__(NT, 1) + register-pinning of
// the 32 per-lane W_hh values inside the t-loop. Rounds 0/2/6 all reported
// VGPR_Count=36, which cannot hold w[4][8]+h+acc (>=55): the compiler was
// refetching weights (L1/L2 reload or AGPR shuffle) every step under its
// default occupancy target. Grid = 1 block/CU, so occupancy is free to drop;
// the empty asm forces w live in true VGPRs each iteration (0 instructions).
__global__ __launch_bounds__(NT, 1) void rnn_kernel(
    const float* __restrict__ x,     // [B,T,I]
    const float* __restrict__ Wih,   // [H,I]
    const float* __restrict__ Whh,   // [H,H]
    const float* __restrict__ bih,   // [H]
    const float* __restrict__ bhh,   // [H]
    const float* __restrict__ h0,    // [1,H]
    const float* __restrict__ Wout,  // [O,H]
    const float* __restrict__ bout,  // [O]
    float* __restrict__ out,         // [B,T,O]
    float* __restrict__ hid)         // [B,T,H]
{
    __shared__ __align__(16) float4 xs[TT];       // (x0,x1,x2,pad) per t
    __shared__ __align__(16) float hbuf[2][HH];   // double-buffered hidden (psi layout)
    __shared__ __align__(16) float psum[2][OO * 16];  // projection partials

    const int tid = threadIdx.x;
    const int b = blockIdx.x;

    // --- stage inputs; init h(0) in psi layout ---
    const float* xb = x + (size_t)b * TT * II;
    for (int idx = tid; idx < TT * II; idx += NT) {
        int t = idx / 3;
        int c = idx - t * 3;
        ((float*)&xs[t])[c] = xb[idx];
    }
    if (tid < HH) hbuf[0][4 * psi(tid >> 2) + (tid & 3)] = h0[tid];

    if (tid < 512) {
        // ================= compute waves =================
        const int lane = tid & 63;
        const int wv   = tid >> 6;       // wave 0..7
        const int og   = lane >> 4;      // output-group (16-lane DPP row) 0..3
        const int s    = lane & 15;      // K-segment: k in [8s, 8s+8)
        const int obase = wv * 16 + og * 4;
        const int u    = s ^ (15 * (s >> 3));  // mirror-symmetric finisher id

        // W_hh[obase+j][8s .. 8s+8] for j=0..3 (32 VGPRs)
        float w[4][8];
#pragma unroll
        for (int j = 0; j < 4; ++j) {
            const float* wr = Whh + (size_t)(obase + j) * HH + 8 * s;
            float4 v1 = ((const float4*)wr)[0];
            float4 v2 = ((const float4*)wr)[1];
            w[j][0] = v1.x; w[j][1] = v1.y; w[j][2] = v1.z; w[j][3] = v1.w;
            w[j][4] = v2.x; w[j][5] = v2.y; w[j][6] = v2.z; w[j][7] = v2.w;
        }
        // finisher lane's input-projection row (u<4 lanes use it; clamp rest)
        const int ru = obase + (u & 3);
        const float wiu0 = Wih[ru * II + 0];
        const float wiu1 = Wih[ru * II + 1];
        const float wiu2 = Wih[ru * II + 2];
        const float biasu = bih[ru] + bhh[ru];
        // write slot for lane s<4: logical h = obase+s -> chunk wv*4+og, elem s
        const int wpos = 4 * psi(wv * 4 + og) + s;

        bar_lds();

        auto cstep = [&](int t, const float* hcur, float* hnext) {
            // logical h[8s..8s+4] and h[8s+4..8s+8] through psi layout
            float4 h1 = ((const float4*)hcur)[s];
            float4 h2 = ((const float4*)hcur)[16 + s];
            // 4 outputs x 8 MACs, paired even/odd
            float a0e = 0.f, a0o = 0.f, a1e = 0.f, a1o = 0.f;
            float a2e = 0.f, a2o = 0.f, a3e = 0.f, a3o = 0.f;
            a0e = fmaf(w[0][0], h1.x, a0e); a0o = fmaf(w[0][1], h1.y, a0o);
            a0e = fmaf(w[0][2], h1.z, a0e); a0o = fmaf(w[0][3], h1.w, a0o);
            a0e = fmaf(w[0][4], h2.x, a0e); a0o = fmaf(w[0][5], h2.y, a0o);
            a0e = fmaf(w[0][6], h2.z, a0e); a0o = fmaf(w[0][7], h2.w, a0o);
            a1e = fmaf(w[1][0], h1.x, a1e); a1o = fmaf(w[1][1], h1.y, a1o);
            a1e = fmaf(w[1][2], h1.z, a1e); a1o = fmaf(w[1][3], h1.w, a1o);
            a1e = fmaf(w[1][4], h2.x, a1e); a1o = fmaf(w[1][5], h2.y, a1o);
            a1e = fmaf(w[1][6], h2.z, a1e); a1o = fmaf(w[1][7], h2.w, a1o);
            a2e = fmaf(w[2][0], h1.x, a2e); a2o = fmaf(w[2][1], h1.y, a2o);
            a2e = fmaf(w[2][2], h1.z, a2e); a2o = fmaf(w[2][3], h1.w, a2o);
            a2e = fmaf(w[2][4], h2.x, a2e); a2o = fmaf(w[2][5], h2.y, a2o);
            a2e = fmaf(w[2][6], h2.z, a2e); a2o = fmaf(w[2][7], h2.w, a2o);
            a3e = fmaf(w[3][0], h1.x, a3e); a3o = fmaf(w[3][1], h1.y, a3o);
            a3e = fmaf(w[3][2], h1.z, a3e); a3o = fmaf(w[3][3], h1.w, a3o);
            a3e = fmaf(w[3][4], h2.x, a3e); a3o = fmaf(w[3][5], h2.y, a3o);
            a3e = fmaf(w[3][6], h2.z, a3e); a3o = fmaf(w[3][7], h2.w, a3o);
            float a0 = a0e + a0o, a1 = a1e + a1o;
            float a2 = a2e + a2o, a3 = a3e + a3o;
            // 3 DPP levels -> each 8-lane half holds its half-sum
            a0 = dpp_add<DPP_XOR1>(a0); a0 = dpp_add<DPP_XOR2>(a0); a0 = dpp_add<DPP_HMIR>(a0);
            a1 = dpp_add<DPP_XOR1>(a1); a1 = dpp_add<DPP_XOR2>(a1); a1 = dpp_add<DPP_HMIR>(a1);
            a2 = dpp_add<DPP_XOR1>(a2); a2 = dpp_add<DPP_XOR2>(a2); a2 = dpp_add<DPP_HMIR>(a2);
            a3 = dpp_add<DPP_XOR1>(a3); a3 = dpp_add<DPP_XOR2>(a3); a3 = dpp_add<DPP_HMIR>(a3);
            // distributed finish: lane u selects output u; row_mirror pairs
            // lane s with s^15 (same u in the other half) -> full 16-lane sum
            float asel = a0;
            asel = (u == 1) ? a1 : asel;
            asel = (u == 2) ? a2 : asel;
            asel = (u == 3) ? a3 : asel;
            asel = dpp_add<DPP_MIRR>(asel);
            float4 xv = xs[t];  // wave-uniform broadcast
            float xp = fmaf(xv.z, wiu2, fmaf(xv.y, wiu1, fmaf(xv.x, wiu0, biasu)));
            float val = fast_tanh(asel + xp);
            if (s < 4) hnext[wpos] = val;
            bar_lds();
        };

        for (int t = 0; t < TT; t += 2) {
            // Pin the weight block in true VGPRs every iteration (emits nothing;
            // defeats load-sinking / AGPR-parking of w under occupancy pressure).
            asm volatile("" : "+v"(w[0][0]), "+v"(w[0][1]), "+v"(w[0][2]), "+v"(w[0][3]),
                              "+v"(w[0][4]), "+v"(w[0][5]), "+v"(w[0][6]), "+v"(w[0][7]),
                              "+v"(w[1][0]), "+v"(w[1][1]), "+v"(w[1][2]), "+v"(w[1][3]),
                              "+v"(w[1][4]), "+v"(w[1][5]), "+v"(w[1][6]), "+v"(w[1][7]));
            asm volatile("" : "+v"(w[2][0]), "+v"(w[2][1]), "+v"(w[2][2]), "+v"(w[2][3]),
                              "+v"(w[2][4]), "+v"(w[2][5]), "+v"(w[2][6]), "+v"(w[2][7]),
                              "+v"(w[3][0]), "+v"(w[3][1]), "+v"(w[3][2]), "+v"(w[3][3]),
                              "+v"(w[3][4]), "+v"(w[3][5]), "+v"(w[3][6]), "+v"(w[3][7]));
            cstep(t, hbuf[0], hbuf[1]);
            cstep(t + 1, hbuf[1], hbuf[0]);
        }
    } else {
        // ================= store + projection wave =================
        const int L = tid - 512;  // lane 0..63; owns logical h = 2L, 2L+1
        const float w00 = Wout[0 * HH + 2 * L], w01 = Wout[0 * HH + 2 * L + 1];
        const float w10 = Wout[1 * HH + 2 * L], w11 = Wout[1 * HH + 2 * L + 1];
        const float w20 = Wout[2 * HH + 2 * L], w21 = Wout[2 * HH + 2 * L + 1];
        const float bL = (L == 0) ? bout[0] : (L == 1) ? bout[1]
                       : (L == 2) ? bout[2] : 0.f;
        float* ob = out + (size_t)b * TT * OO;
        float* hb = hid + (size_t)b * TT * HH;
        const int q = L >> 2;               // quad id 0..15
        const bool qlead = (L & 3) == 0;
        // logical h[2L] through psi layout (float2-aligned)
        const int fpos = 4 * psi(L >> 1) + 2 * (L & 1);

        bar_lds();

        auto sstep = [&](int t, const float* hcur, float* psA, const float* psB) {
            // phase A: hid[t-1] store + quad partials for out[t-1] -> psA
            if (t >= 1) {
                const float2 hv = *(const float2*)(hcur + fpos);
                ((float2*)(hb + (size_t)(t - 1) * HH))[L] = hv;  // coalesced 512B
                float p0 = fmaf(hv.x, w00, hv.y * w01);
                float p1 = fmaf(hv.x, w10, hv.y * w11);
                float p2 = fmaf(hv.x, w20, hv.y * w21);
                p0 = quad_reduce(p0);
                p1 = quad_reduce(p1);
                p2 = quad_reduce(p2);
                if (qlead) {
                    psA[0 * 16 + q] = p0;
                    psA[1 * 16 + q] = p1;
                    psA[2 * 16 + q] = p2;
                }
            }
            // phase B: finish out[t-2] from previous window's partials (psB).
            if (t >= 2 && L < OO) {
                const float4* pp = (const float4*)(psB + L * 16);
                float4 u0 = pp[0], u1 = pp[1], u2 = pp[2], u3 = pp[3];
                float s0 = ((u0.x + u0.y) + (u0.z + u0.w)) +
                           ((u1.x + u1.y) + (u1.z + u1.w));
                float s1 = ((u2.x + u2.y) + (u2.z + u2.w)) +
                           ((u3.x + u3.y) + (u3.z + u3.w));
                ob[(size_t)(t - 2) * OO + L] = s0 + s1 + bL;
            }
            bar_lds();
        };

        for (int t = 0; t < TT; t += 2) {
            sstep(t, hbuf[0], psum[0], psum[1]);
            sstep(t + 1, hbuf[1], psum[1], psum[0]);
        }

        // tail (no barriers; compute waves exited, barrier counts match):
        // hbuf[0] = h[TT], psum[1] holds partials for out[TT-2].
        {
            const float2 hv = *(const float2*)(&hbuf[0][0] + fpos);
            ((float2*)(hb + (size_t)(TT - 1) * HH))[L] = hv;
            float p0 = fmaf(hv.x, w00, hv.y * w01);
            float p1 = fmaf(hv.x, w10, hv.y * w11);
            float p2 = fmaf(hv.x, w20, hv.y * w21);
            p0 = quad_reduce(p0);
            p1 = quad_reduce(p1);
            p2 = quad_reduce(p2);
            if (qlead) {
                psum[0][0 * 16 + q] = p0;
                psum[0][1 * 16 + q] = p1;
                psum[0][2 * 16 + q] = p2;
            }
            if (L < OO) {
                const float4* pp = (const float4*)(psum[1] + L * 16);
                float4 u0 = pp[0], u1 = pp[1], u2 = pp[2], u3 = pp[3];
                float s0 = ((u0.x + u0.y) + (u0.z + u0.w)) +
                           ((u1.x + u1.y) + (u1.z + u1.w));
                float s1 = ((u2.x + u2.y) + (u2.z + u2.w)) +
                           ((u3.x + u3.y) + (u3.z + u3.w));
                ob[(size_t)(TT - 2) * OO + L] = s0 + s1 + bL;
                const float4* pq = (const float4*)(psum[0] + L * 16);
                float4 v0 = pq[0], v1 = pq[1], v2 = pq[2], v3 = pq[3];
                float r0 = ((v0.x + v0.y) + (v0.z + v0.w)) +
                           ((v1.x + v1.y) + (v1.z + v1.w));
                float r1 = ((v2.x + v2.y) + (v2.z + v2.w)) +
                           ((v3.x + v3.y) + (v3.z + v3.w));
                ob[(size_t)(TT - 1) * OO + L] = r0 + r1 + bL;
            }
        }
    }
}

extern "C" void kernel_launch(void* const* d_in, const int* in_sizes, int n_in,
                              void* d_out, int out_size, void* d_ws, size_t ws_size,
                              hipStream_t stream) {
    const float* x    = (const float*)d_in[0];  // [256,1024,3]
    const float* Wih  = (const float*)d_in[1];  // [128,3]
    const float* Whh  = (const float*)d_in[2];  // [128,128]
    const float* bih  = (const float*)d_in[3];  // [128]
    const float* bhh  = (const float*)d_in[4];  // [128]
    const float* h0   = (const float*)d_in[5];  // [1,128]
    const float* Wout = (const float*)d_in[6];  // [3,128]
    const float* bout = (const float*)d_in[7];  // [3]

    float* out = (float*)d_out;                 // [B,T,O] first
    float* hid = out + (size_t)BB * TT * OO;    // then [B,T,H]

    rnn_kernel<<<BB, NT, 0, stream>>>(x, Wih, Whh, bih, bhh, h0, Wout, bout, out, hid);
}